// Round 17
// baseline (112.598 us; speedup 1.0000x reference)
//
#include <hip/hip_runtime.h>
#include <cmath>
#include <complex>

// sr=16000, band 500-7000, order 8 -> 16 poles = 8 real 2nd-order sections.
#define NB    32
#define LX    262144
#define PAD   51                      // padlen = 3*17
#define LTOT  (LX + 2 * PAD)          // 262246
#define CM    16                      // samples per chunk (= per thread)
#define F_PAD 922                     // zero-input front pad
#define LPAD  (LTOT + F_PAD)          // 263168 = 257 * 1024 (tile-aligned)
#define CPB   64                      // threads per block = ONE WAVE
#define TILE  (CPB * CM)              // 1024 samples per wave-tile
#define NTILE (LPAD / TILE)           // 257 tiles per row
#define NP    8
#define LDSR  17                      // floats per LDS lane-row (gcd(17,32)=1)

struct CoeffsS { float a1[NP], a2[NP], b0[NP], b1[NP], g1a[NP], g1b[NP], c0; };
// lv[k][q] = (A_q^CM)^(2^k) = M0^(2^k), k=0..5; lv[6] = M0^64 = tile transition
struct LvS { float lv[7][NP][4]; };

// ---------------------------------------------------------------------------
// init: build mt[t*8+q] = M0^t (t=0..63) via binary exponentiation.
__global__ void k_init(float4* __restrict__ mt, LvS L) {
    int id = blockIdx.x * 256 + threadIdx.x;
    if (id >= 512) return;
    int t = id >> 3, q = id & 7;
    float m0 = 1.f, m1 = 0.f, m2 = 0.f, m3 = 1.f;
    for (int k = 0; k < 6; k++)
        if ((t >> k) & 1) {
            float a0 = L.lv[k][q][0], a1 = L.lv[k][q][1];
            float a2 = L.lv[k][q][2], a3 = L.lv[k][q][3];
            float n0 = a0 * m0 + a1 * m2, n1 = a0 * m1 + a1 * m3;
            float n2 = a2 * m0 + a3 * m2, n3 = a2 * m1 + a3 * m3;
            m0 = n0; m1 = n1; m2 = n2; m3 = n3;
        }
    mt[id] = make_float4(m0, m1, m2, m3);
}

// ---------------------------------------------------------------------------
// u-loader pass A: chunk c covers t' = c*CM..+CM, real t = t' - F_PAD.
__device__ __forceinline__ void load_uA(const float* __restrict__ x,
                                        float base, int c, float (&u)[CM]) {
    int t0 = c * CM - F_PAD;
    if (t0 >= PAD && t0 + CM <= PAD + LX) {
        const float* xs = x + (t0 - PAD);
#pragma unroll
        for (int m = 0; m < CM / 4; m++) {
            float4 v = *reinterpret_cast<const float4*>(xs + 4 * m);
            u[4 * m] = v.x - base; u[4 * m + 1] = v.y - base;
            u[4 * m + 2] = v.z - base; u[4 * m + 3] = v.w - base;
        }
    } else {
#pragma unroll
        for (int i = 0; i < CM; i++) {
            int t = t0 + i;
            float uu;
            if (t < 0) uu = 0.f;                        // front pad
            else {
                float e;
                if (t < PAD)            e = 2.0f * x[0] - x[PAD - t];
                else if (t < PAD + LX)  e = x[t - PAD];
                else                    e = 2.0f * x[LX - 1] - x[2 * LX + PAD - 2 - t];
                uu = e - base;
            }
            u[i] = uu;
        }
    }
}

// local chunk recurrence from zero state
__device__ __forceinline__ void local_states(const float (&u)[CM], const CoeffsS& C,
                                             float (&w1)[NP], float (&w2)[NP]) {
#pragma unroll
    for (int q = 0; q < NP; q++) { w1[q] = 0.f; w2[q] = 0.f; }
#pragma unroll
    for (int i = 0; i < CM; i++) {
        float uu = u[i];
#pragma unroll
        for (int q = 0; q < NP; q++) {
            float wt = fmaf(C.a1[q], w1[q], fmaf(C.a2[q], w2[q], uu));
            w2[q] = w1[q]; w1[q] = wt;
        }
    }
}

// 64-wide Hillis-Steele inclusive affine scan through LDS. One wave per
// block: __syncthreads() degenerates to a waitcnt.
__device__ __forceinline__ void scan64(float2* sc2, int pos, const LvS& L,
                                       float (&w1)[NP], float (&w2)[NP]) {
#pragma unroll
    for (int q = 0; q < NP; q++) sc2[q * 64 + pos] = make_float2(w1[q], w2[q]);
    __syncthreads();
#pragma unroll
    for (int k = 0; k < 6; k++) {
        int d = 1 << k;
        float2 o[NP];
        if (pos >= d) {
#pragma unroll
            for (int q = 0; q < NP; q++) o[q] = sc2[q * 64 + pos - d];
        }
        __syncthreads();
        if (pos >= d) {
#pragma unroll
            for (int q = 0; q < NP; q++) {
                w1[q] = fmaf(L.lv[k][q][0], o[q].x, fmaf(L.lv[k][q][1], o[q].y, w1[q]));
                w2[q] = fmaf(L.lv[k][q][2], o[q].x, fmaf(L.lv[k][q][3], o[q].y, w2[q]));
            }
        }
#pragma unroll
        for (int q = 0; q < NP; q++) sc2[q * 64 + pos] = make_float2(w1[q], w2[q]);
        __syncthreads();
    }
}

// ---------------------------------------------------------------------------
// K1 (pass A): per-tile aggregates from zero init. One wave per tile.
__global__ __launch_bounds__(64) void k_agg(const float* __restrict__ audio,
                                            float2* __restrict__ agg,
                                            CoeffsS C, LvS L) {
    __shared__ float2 sc2[NP * 64];
    int tid = threadIdx.x, tx = blockIdx.x, b = blockIdx.y;
    const float* x = audio + (size_t)b * LX;
    float base = 2.0f * x[0] - x[PAD];
    float u[CM];
    load_uA(x, base, tx * CPB + tid, u);
    float w1[NP], w2[NP];
    local_states(u, C, w1, w2);
    scan64(sc2, tid, L, w1, w2);
    if (tid < NP)
        agg[(size_t)(b * NTILE + tx) * NP + tid] = sc2[tid * 64 + 63];
}

// ---------------------------------------------------------------------------
// K2: per-row serial walk over NTILE tile aggregates (LDS-staged) -> exclusive
// tile entry states X. CORR=1 (pass B): subtract base*g1024 per aggregate.
template <int CORR>
__global__ __launch_bounds__(256) void k_prefix(const float2* __restrict__ agg,
                                                float2* __restrict__ xpre,
                                                const float* __restrict__ ybuf,
                                                CoeffsS C, LvS L) {
    __shared__ float2 sa[NTILE * NP];     // 16448 B
    int b = blockIdx.x, tid = threadIdx.x;
    const float2* ab = agg + (size_t)b * NTILE * NP;
    for (int id = tid; id < NTILE * NP; id += 256) sa[id] = ab[id];
    __syncthreads();
    if (tid < NP) {
        int q = tid;
        float B0 = L.lv[6][q][0], B1 = L.lv[6][q][1];   // M0^64 = A^1024
        float B2 = L.lv[6][q][2], B3 = L.lv[6][q][3];
        float cga = 0.f, cgb = 0.f;
        if (CORR) {
            float base = ybuf[(size_t)b * LPAD];
            cga = base * C.g1a[q]; cgb = base * C.g1b[q];
        }
        float X1 = 0.f, X2 = 0.f;
        for (int t = 0; t < NTILE; t++) {
            xpre[(size_t)(b * NTILE + t) * NP + q] = make_float2(X1, X2);
            float2 f = sa[t * NP + q];
            float n1 = fmaf(B0, X1, fmaf(B1, X2, f.x - cga));
            float n2 = fmaf(B2, X1, fmaf(B3, X2, f.y - cgb));
            X1 = n1; X2 = n2;
        }
    }
}

// ---------------------------------------------------------------------------
// K3: one wave per tile. scan64; entry from precomputed tile X; replay;
// per-wave LDS stage; coalesced store.
// PASS 0: in=audio -> ybuf reversed; also emits raw pass-B tile aggregates.
// PASS 1: in=ybuf -> final out (un-reverse + trim PAD).
template <int PASS>
__global__ __launch_bounds__(64) void k_full(const float* __restrict__ in,
                                             float* __restrict__ outp,
                                             const float2* __restrict__ xpre,
                                             float2* __restrict__ aggB,
                                             const float4* __restrict__ mt,
                                             CoeffsS C, LvS L) {
    __shared__ __align__(16) float lds[CPB * LDSR];   // 4352 B (aliases sc2)
    __shared__ float2 xb[NP];
    float2* sc2 = reinterpret_cast<float2*>(lds);     // first 4 KB: scan region
    int tid = threadIdx.x, tx = blockIdx.x, b = blockIdx.y;
    int c = tx * CPB + tid;

    // ---- load u ----
    float u[CM];
    if (PASS == 0) {
        const float* x = in + (size_t)b * LX;
        float base = 2.0f * x[0] - x[PAD];
        load_uA(x, base, c, u);
    } else {
        const float* yb = in + (size_t)b * LPAD;
        float base = yb[0];               // = y[LTOT-1]
        const float* ys = yb + (size_t)c * CM;
#pragma unroll
        for (int m = 0; m < CM / 4; m++) {
            float4 v = *reinterpret_cast<const float4*>(ys + 4 * m);
            u[4 * m] = v.x - base; u[4 * m + 1] = v.y - base;
            u[4 * m + 2] = v.z - base; u[4 * m + 3] = v.w - base;
        }
    }

    // tile entry X (precomputed); visible after scan's first barrier
    if (tid < NP) xb[tid] = xpre[(size_t)(b * NTILE + tx) * NP + tid];

    // ---- local states + wave-wide LDS scan ----
    float w1[NP], w2[NP];
    local_states(u, C, w1, w2);
    scan64(sc2, tid, L, w1, w2);

    // ---- entry = exclusive + M0^tid * X; replay u -> y (registers) ----
#pragma unroll
    for (int q = 0; q < NP; q++) {
        float2 ev = (tid > 0) ? sc2[q * 64 + tid - 1] : make_float2(0.f, 0.f);
        float4 m4 = mt[tid * NP + q];
        float2 X = xb[q];
        w1[q] = fmaf(m4.x, X.x, fmaf(m4.y, X.y, ev.x));
        w2[q] = fmaf(m4.z, X.x, fmaf(m4.w, X.y, ev.y));
    }
#pragma unroll
    for (int i = 0; i < CM; i++) {
        float uu = u[i];
        float y = C.c0 * uu;
#pragma unroll
        for (int q = 0; q < NP; q++) {
            float wt = fmaf(C.a1[q], w1[q], fmaf(C.a2[q], w2[q], uu));
            y = fmaf(C.b0[q], wt, fmaf(C.b1[q], w1[q], y));
            w2[q] = w1[q]; w1[q] = wt;
        }
        u[i] = y;                          // u now holds y
    }

    if (PASS == 0) {
        // ---- fused raw pass-B tile aggregates: reverse rec + reverse scan ----
        float t1[NP], t2[NP];
#pragma unroll
        for (int q = 0; q < NP; q++) { t1[q] = 0.f; t2[q] = 0.f; }
#pragma unroll
        for (int i = CM - 1; i >= 0; --i) {   // pass-B order within chunk
            float wvv = u[i];
#pragma unroll
            for (int q = 0; q < NP; q++) {
                float wt = fmaf(C.a1[q], t1[q], fmaf(C.a2[q], t2[q], wvv));
                t2[q] = t1[q]; t1[q] = wt;
            }
        }
        __syncthreads();                      // sc2 free for reuse
        scan64(sc2, 63 - tid, L, t1, t2);
        if (tid < NP)
            aggB[(size_t)(b * NTILE + (NTILE - 1 - tx)) * NP + tid] =
                sc2[tid * 64 + 63];
    }

    // ---- stage y to LDS (scalar, stride-17); store ----
    __syncthreads();
#pragma unroll
    for (int i = 0; i < CM; i++) lds[tid * LDSR + i] = u[i];
    __syncthreads();

    if (PASS == 0) {
        // coalesced REVERSED store of this tile's 1024 samples
        float4* yb4 = reinterpret_cast<float4*>(
            outp + (size_t)b * LPAD + (size_t)(NTILE - 1 - tx) * TILE);
#pragma unroll
        for (int k = 0; k < 4; k++) {
            int o4 = tid + 64 * k;             // 0..255
            int ts = 63 - (o4 >> 2);
            int ih = 15 - 4 * (o4 & 3);
            const float* r = &lds[ts * LDSR];
            yb4[o4] = make_float4(r[ih], r[ih - 1], r[ih - 2], r[ih - 3]);
        }
    } else {
        // out[j] = y2[s], j = (LTOT-1-PAD) - s  (un-reverse + trim PAD)
        float* ob = outp + (size_t)b * LX;
        int J0 = (LTOT - 1 - PAD) - tx * TILE;
#pragma unroll
        for (int it = 0; it < CM; it++) {
            int o = it * 64 + tid;
            int j = J0 - o;
            if (j >= 0 && j < LX)
                ob[j] = lds[(o >> 4) * LDSR + (o & 15)];
        }
    }
}

// ---------------------------------------------------------------------------
// Host: scipy butter(8,[500,7000]/8000,'bandpass') -> real 2nd-order sections
// + chunk-transition (A^16) power levels + exact 1024-step const-input pair.
static void compute_coeffs(CoeffsS& C, LvS& L) {
    using cd = std::complex<double>;
    const int N = 8;
    const double sr = 16000.0, lo = 500.0, hi = 7000.0, fs = 2.0;
    double w0 = 2.0 * fs * std::tan(M_PI * (2.0 * lo / sr) / fs);
    double w1 = 2.0 * fs * std::tan(M_PI * (2.0 * hi / sr) / fs);
    double bw = w1 - w0, wo = std::sqrt(w0 * w1);
    cd pbp[16];
    for (int k = 0; k < N; k++) {
        int m = -N + 1 + 2 * k;
        cd pl = -std::exp(cd(0.0, M_PI * m / (2.0 * N)));
        pl *= bw / 2.0;
        cd s = std::sqrt(pl * pl - cd(wo * wo, 0.0));
        pbp[k] = pl + s; pbp[k + N] = pl - s;
    }
    double kbp = std::pow(bw, (double)N);
    const double fs2 = 4.0;
    cd pd[16], denom = 1.0;
    for (int i = 0; i < 16; i++) {
        pd[i] = (cd(fs2, 0.0) + pbp[i]) / (cd(fs2, 0.0) - pbp[i]);
        denom *= (cd(fs2, 0.0) - pbp[i]);
    }
    double kd = kbp * std::real(cd(std::pow(fs2, 8.0), 0.0) / denom);
    cd prodp = 1.0;
    for (int i = 0; i < 16; i++) prodp *= pd[i];
    cd c0 = cd(kd, 0.0) / prodp;
    int n = 0;
    for (int i = 0; i < 16; i++) {
        if (pd[i].imag() <= 0.0) continue;
        cd inv = 1.0 / pd[i];
        cd t1 = cd(1.0, 0.0) - inv, t2 = cd(1.0, 0.0) + inv;
        cd numr = cd(kd, 0.0);
        for (int k = 0; k < 8; k++) numr *= t1;
        for (int k = 0; k < 8; k++) numr *= t2;
        cd den = 1.0;
        for (int j = 0; j < 16; j++)
            if (j != i) den *= (cd(1.0, 0.0) - pd[j] * inv);
        cd r2 = 2.0 * numr / den;             // conjugate pair folded
        if (n < NP) {
            double a1 = 2.0 * pd[i].real();
            double a2 = -std::norm(pd[i]);
            C.a1[n] = (float)a1; C.a2[n] = (float)a2;
            C.b0[n] = (float)r2.real();
            C.b1[n] = (float)(-(r2.real() * pd[i].real() + r2.imag() * pd[i].imag()));
            // exact 1024-step constant-input response pair (prefixB correction)
            double gw1 = 0.0, gw2 = 0.0;
            for (int k = 0; k < 1024; k++) {
                double gt = a1 * gw1 + a2 * gw2 + 1.0; gw2 = gw1; gw1 = gt;
            }
            C.g1a[n] = (float)gw1; C.g1b[n] = (float)gw2;
            double M[4] = { a1, a2, 1.0, 0.0 };       // A = [[a1,a2],[1,0]]
            for (int s = 0; s < 4; s++) {             // M0 = A^16
                double q0 = M[0] * M[0] + M[1] * M[2], q1 = M[0] * M[1] + M[1] * M[3];
                double q2 = M[2] * M[0] + M[3] * M[2], q3 = M[2] * M[1] + M[3] * M[3];
                M[0] = q0; M[1] = q1; M[2] = q2; M[3] = q3;
            }
            for (int k = 0; k < 7; k++) {             // lv[k] = M0^(2^k)
                for (int j = 0; j < 4; j++) L.lv[k][n][j] = (float)M[j];
                double q0 = M[0] * M[0] + M[1] * M[2], q1 = M[0] * M[1] + M[1] * M[3];
                double q2 = M[2] * M[0] + M[3] * M[2], q3 = M[2] * M[1] + M[3] * M[3];
                M[0] = q0; M[1] = q1; M[2] = q2; M[3] = q3;
            }
            n++;
        }
    }
    C.c0 = (float)c0.real();
}

extern "C" void kernel_launch(void* const* d_in, const int* in_sizes, int n_in,
                              void* d_out, int out_size, void* d_ws, size_t ws_size,
                              hipStream_t stream) {
    const float* audio = (const float*)d_in[0];
    float* out = (float*)d_out;

    CoeffsS C; LvS L;
    compute_coeffs(C, L);

    // ws: ybuf 33.7MB + mt 8KB + aggA/aggB/xpreA/xpreB 526KB each
    char* ws = (char*)d_ws;
    size_t o = 0;
    auto alloc = [&](size_t bytes) { size_t r = o; o += (bytes + 255) & ~(size_t)255; return r; };
    float*  ybuf  = (float*)(ws + alloc((size_t)NB * LPAD * sizeof(float)));
    float4* mt    = (float4*)(ws + alloc(512 * sizeof(float4)));
    float2* aggA  = (float2*)(ws + alloc((size_t)NB * NTILE * NP * sizeof(float2)));
    float2* aggB  = (float2*)(ws + alloc((size_t)NB * NTILE * NP * sizeof(float2)));
    float2* xpreA = (float2*)(ws + alloc((size_t)NB * NTILE * NP * sizeof(float2)));
    float2* xpreB = (float2*)(ws + alloc((size_t)NB * NTILE * NP * sizeof(float2)));

    dim3 blkw(64), blk(256), g(NTILE, NB);

    k_init     <<<2,  256, 0, stream>>>(mt, L);
    k_agg      <<<g,  blkw, 0, stream>>>(audio, aggA, C, L);
    k_prefix<0><<<NB, blk,  0, stream>>>(aggA, xpreA, ybuf, C, L);
    k_full<0>  <<<g,  blkw, 0, stream>>>(audio, ybuf, xpreA, aggB, mt, C, L);
    k_prefix<1><<<NB, blk,  0, stream>>>(aggB, xpreB, ybuf, C, L);
    k_full<1>  <<<g,  blkw, 0, stream>>>(ybuf, out, xpreB, nullptr, mt, C, L);
}

// Round 18
// 102.335 us; speedup vs baseline: 1.1003x; 1.1003x over previous
//
#include <hip/hip_runtime.h>
#include <cmath>
#include <complex>

// sr=16000, band 500-7000, order 8 -> 16 poles = 8 real 2nd-order sections.
#define NB    32
#define LX    262144
#define PAD   51                      // padlen = 3*17
#define LTOT  (LX + 2 * PAD)          // 262246
#define CM    32                      // samples per chunk (= per thread)
#define F_PAD 1946                    // zero-input front pad
#define LPAD  (LTOT + F_PAD)          // 264192 = 129 * 2048 (tile-aligned)
#define CPB   64                      // threads per block = ONE WAVE
#define TILE  (CPB * CM)              // 2048 samples per wave-tile
#define NTILE (LPAD / TILE)           // 129 tiles per row
#define NP    8
#define LDSR  34                      // floats per LDS lane-row (proven: 0 conflicts)
#define WIN   16                      // combine window (chunks); M0^16=A^512 ~ 2e-6

struct CoeffsS { float a1[NP], a2[NP], b0[NP], b1[NP], g1a[NP], g1b[NP], c0; };
// lv[k][q] = (A_q^CM)^(2^k) = M0^(2^k), k=0..5; lv[6] = M0^64 = tile transition
struct LvS { float lv[7][NP][4]; };

// ---------------------------------------------------------------------------
// init: build mt[t*8+q] = M0^t (t=0..63) via binary exponentiation.
__global__ void k_init(float4* __restrict__ mt, LvS L) {
    int id = blockIdx.x * 256 + threadIdx.x;
    if (id >= 512) return;
    int t = id >> 3, q = id & 7;
    float m0 = 1.f, m1 = 0.f, m2 = 0.f, m3 = 1.f;
    for (int k = 0; k < 6; k++)
        if ((t >> k) & 1) {
            float a0 = L.lv[k][q][0], a1 = L.lv[k][q][1];
            float a2 = L.lv[k][q][2], a3 = L.lv[k][q][3];
            float n0 = a0 * m0 + a1 * m2, n1 = a0 * m1 + a1 * m3;
            float n2 = a2 * m0 + a3 * m2, n3 = a2 * m1 + a3 * m3;
            m0 = n0; m1 = n1; m2 = n2; m3 = n3;
        }
    mt[id] = make_float4(m0, m1, m2, m3);
}

// ---------------------------------------------------------------------------
// u-loader pass A: chunk c covers t' = c*CM..+CM, real t = t' - F_PAD.
__device__ __forceinline__ void load_uA(const float* __restrict__ x,
                                        float base, int c, float (&u)[CM]) {
    int t0 = c * CM - F_PAD;
    if (t0 >= PAD && t0 + CM <= PAD + LX) {
        const float* xs = x + (t0 - PAD);
#pragma unroll
        for (int m = 0; m < CM / 4; m++) {
            float4 v = *reinterpret_cast<const float4*>(xs + 4 * m);
            u[4 * m] = v.x - base; u[4 * m + 1] = v.y - base;
            u[4 * m + 2] = v.z - base; u[4 * m + 3] = v.w - base;
        }
    } else {
#pragma unroll
        for (int i = 0; i < CM; i++) {
            int t = t0 + i;
            float uu;
            if (t < 0) uu = 0.f;                        // front pad
            else {
                float e;
                if (t < PAD)            e = 2.0f * x[0] - x[PAD - t];
                else if (t < PAD + LX)  e = x[t - PAD];
                else                    e = 2.0f * x[LX - 1] - x[2 * LX + PAD - 2 - t];
                uu = e - base;
            }
            u[i] = uu;
        }
    }
}

// local chunk recurrence from zero state
__device__ __forceinline__ void local_states(const float (&u)[CM], const CoeffsS& C,
                                             float (&w1)[NP], float (&w2)[NP]) {
#pragma unroll
    for (int q = 0; q < NP; q++) { w1[q] = 0.f; w2[q] = 0.f; }
#pragma unroll
    for (int i = 0; i < CM; i++) {
        float uu = u[i];
#pragma unroll
        for (int q = 0; q < NP; q++) {
            float wt = fmaf(C.a1[q], w1[q], fmaf(C.a2[q], w2[q], uu));
            w2[q] = w1[q]; w1[q] = wt;
        }
    }
}

// pack per-lane chunk states into LDS: sc4[p*64+l] = (w1[2p],w2[2p],w1[2p+1],w2[2p+1])
__device__ __forceinline__ void pack_states(float4* sc4, int tid,
                                            const float (&w1)[NP], const float (&w2)[NP]) {
#pragma unroll
    for (int p = 0; p < 4; p++)
        sc4[p * 64 + tid] = make_float4(w1[2 * p], w2[2 * p], w1[2 * p + 1], w2[2 * p + 1]);
}

// ---------------------------------------------------------------------------
// K1 (pass A): per-tile aggregates from zero init. One wave per tile.
// aggA = sum_{k=0}^{WIN-1} M0^k f_{63-k}  (truncated; M0^16 ~ 2e-6)
__global__ __launch_bounds__(64) void k_agg(const float* __restrict__ audio,
                                            float2* __restrict__ agg,
                                            const float4* __restrict__ mt,
                                            CoeffsS C, LvS L) {
    __shared__ __align__(16) float4 sc4[4 * 64];
    int tid = threadIdx.x, tx = blockIdx.x, b = blockIdx.y;
    const float* x = audio + (size_t)b * LX;
    float base = 2.0f * x[0] - x[PAD];
    float u[CM];
    load_uA(x, base, tx * CPB + tid, u);
    float w1[NP], w2[NP];
    local_states(u, C, w1, w2);
    pack_states(sc4, tid, w1, w2);
    __syncthreads();
    if (tid < 4) {
        int p = tid;
        float A1a = 0.f, A2a = 0.f, A1b = 0.f, A2b = 0.f;
#pragma unroll
        for (int k = 0; k < WIN; k++) {
            float4 f = sc4[p * 64 + 63 - k];
            float4 ma = mt[k * NP + 2 * p];
            float4 mb = mt[k * NP + 2 * p + 1];
            A1a = fmaf(ma.x, f.x, fmaf(ma.y, f.y, A1a));
            A2a = fmaf(ma.z, f.x, fmaf(ma.w, f.y, A2a));
            A1b = fmaf(mb.x, f.z, fmaf(mb.y, f.w, A1b));
            A2b = fmaf(mb.z, f.z, fmaf(mb.w, f.w, A2b));
        }
        float2* ao = agg + (size_t)(b * NTILE + tx) * NP;
        ao[2 * p]     = make_float2(A1a, A2a);
        ao[2 * p + 1] = make_float2(A1b, A2b);
    }
}

// ---------------------------------------------------------------------------
// K2: per-row serial walk over NTILE tile aggregates (LDS-staged) -> exclusive
// tile entry states X. CORR=1 (pass B): subtract base*g2048 per aggregate.
template <int CORR>
__global__ __launch_bounds__(256) void k_prefix(const float2* __restrict__ agg,
                                                float2* __restrict__ xpre,
                                                const float* __restrict__ ybuf,
                                                CoeffsS C, LvS L) {
    __shared__ float2 sa[NTILE * NP];     // 8256 B
    int b = blockIdx.x, tid = threadIdx.x;
    const float2* ab = agg + (size_t)b * NTILE * NP;
    for (int id = tid; id < NTILE * NP; id += 256) sa[id] = ab[id];
    __syncthreads();
    if (tid < NP) {
        int q = tid;
        float B0 = L.lv[6][q][0], B1 = L.lv[6][q][1];   // M0^64 = A^2048
        float B2 = L.lv[6][q][2], B3 = L.lv[6][q][3];
        float cga = 0.f, cgb = 0.f;
        if (CORR) {
            float base = ybuf[(size_t)b * LPAD];
            cga = base * C.g1a[q]; cgb = base * C.g1b[q];
        }
        float X1 = 0.f, X2 = 0.f;
        for (int t = 0; t < NTILE; t++) {
            xpre[(size_t)(b * NTILE + t) * NP + q] = make_float2(X1, X2);
            float2 f = sa[t * NP + q];
            float n1 = fmaf(B0, X1, fmaf(B1, X2, f.x - cga));
            float n2 = fmaf(B2, X1, fmaf(B3, X2, f.y - cgb));
            X1 = n1; X2 = n2;
        }
    }
}

// ---------------------------------------------------------------------------
// K3: one wave per tile. Truncated-window combine replaces the LDS scan:
// entry_l = M0^l X + sum_{k=1}^{WIN} M0^(k-1) f_{l-k}   (exact for l<WIN).
// PASS 0: in=audio -> ybuf reversed; also emits truncated pass-B aggregates.
// PASS 1: in=ybuf -> final out (un-reverse + trim PAD).
template <int PASS>
__global__ __launch_bounds__(64) void k_full(const float* __restrict__ in,
                                             float* __restrict__ outp,
                                             const float2* __restrict__ xpre,
                                             float2* __restrict__ aggB,
                                             const float4* __restrict__ mt,
                                             CoeffsS C, LvS L) {
    __shared__ __align__(16) float lds[CPB * LDSR];   // 8704 B (aliases sc4)
    __shared__ float2 xb[NP];
    float4* sc4 = reinterpret_cast<float4*>(lds);     // first 4 KB
    int tid = threadIdx.x, tx = blockIdx.x, b = blockIdx.y;
    int c = tx * CPB + tid;

    // ---- load u ----
    float u[CM];
    if (PASS == 0) {
        const float* x = in + (size_t)b * LX;
        float base = 2.0f * x[0] - x[PAD];
        load_uA(x, base, c, u);
    } else {
        const float* yb = in + (size_t)b * LPAD;
        float base = yb[0];               // = y[LTOT-1]
        const float* ys = yb + (size_t)c * CM;
#pragma unroll
        for (int m = 0; m < CM / 4; m++) {
            float4 v = *reinterpret_cast<const float4*>(ys + 4 * m);
            u[4 * m] = v.x - base; u[4 * m + 1] = v.y - base;
            u[4 * m + 2] = v.z - base; u[4 * m + 3] = v.w - base;
        }
    }

    // tile entry X (precomputed)
    if (tid < NP) xb[tid] = xpre[(size_t)(b * NTILE + tx) * NP + tid];

    // ---- local states; publish to LDS ----
    float w1[NP], w2[NP];
    local_states(u, C, w1, w2);
    pack_states(sc4, tid, w1, w2);
    __syncthreads();

    // ---- truncated-window entry combine (independent LDS reads, no chain) ----
    float e1[NP], e2[NP];
#pragma unroll
    for (int q = 0; q < NP; q++) { e1[q] = 0.f; e2[q] = 0.f; }
#pragma unroll
    for (int k = 1; k <= WIN; k++) {
        if (tid >= k) {
#pragma unroll
            for (int p = 0; p < 4; p++) {
                float4 f = sc4[p * 64 + tid - k];
                float4 ma = mt[(k - 1) * NP + 2 * p];
                float4 mb = mt[(k - 1) * NP + 2 * p + 1];
                e1[2 * p]     = fmaf(ma.x, f.x, fmaf(ma.y, f.y, e1[2 * p]));
                e2[2 * p]     = fmaf(ma.z, f.x, fmaf(ma.w, f.y, e2[2 * p]));
                e1[2 * p + 1] = fmaf(mb.x, f.z, fmaf(mb.y, f.w, e1[2 * p + 1]));
                e2[2 * p + 1] = fmaf(mb.z, f.z, fmaf(mb.w, f.w, e2[2 * p + 1]));
            }
        }
    }

    // ---- entry = combine + M0^tid * X; replay u -> y (registers) ----
#pragma unroll
    for (int q = 0; q < NP; q++) {
        float4 m4 = mt[tid * NP + q];
        float2 X = xb[q];
        w1[q] = fmaf(m4.x, X.x, fmaf(m4.y, X.y, e1[q]));
        w2[q] = fmaf(m4.z, X.x, fmaf(m4.w, X.y, e2[q]));
    }
#pragma unroll
    for (int i = 0; i < CM; i++) {
        float uu = u[i];
        float y = C.c0 * uu;
#pragma unroll
        for (int q = 0; q < NP; q++) {
            float wt = fmaf(C.a1[q], w1[q], fmaf(C.a2[q], w2[q], uu));
            y = fmaf(C.b0[q], wt, fmaf(C.b1[q], w1[q], y));
            w2[q] = w1[q]; w1[q] = wt;
        }
        u[i] = y;                          // u now holds y
    }

    if (PASS == 0) {
        // ---- truncated pass-B tile aggregate: aggB = sum_{l<WIN} M0^l g_l ----
        float t1[NP], t2[NP];
#pragma unroll
        for (int q = 0; q < NP; q++) { t1[q] = 0.f; t2[q] = 0.f; }
#pragma unroll
        for (int i = CM - 1; i >= 0; --i) {   // pass-B order within chunk
            float wvv = u[i];
#pragma unroll
            for (int q = 0; q < NP; q++) {
                float wt = fmaf(C.a1[q], t1[q], fmaf(C.a2[q], t2[q], wvv));
                t2[q] = t1[q]; t1[q] = wt;
            }
        }
        __syncthreads();                      // all f-reads done
        pack_states(sc4, tid, t1, t2);
        __syncthreads();
        if (tid < 4) {
            int p = tid;
            float A1a = 0.f, A2a = 0.f, A1b = 0.f, A2b = 0.f;
#pragma unroll
            for (int l = 0; l < WIN; l++) {
                float4 g = sc4[p * 64 + l];
                float4 ma = mt[l * NP + 2 * p];
                float4 mb = mt[l * NP + 2 * p + 1];
                A1a = fmaf(ma.x, g.x, fmaf(ma.y, g.y, A1a));
                A2a = fmaf(ma.z, g.x, fmaf(ma.w, g.y, A2a));
                A1b = fmaf(mb.x, g.z, fmaf(mb.y, g.w, A1b));
                A2b = fmaf(mb.z, g.z, fmaf(mb.w, g.w, A2b));
            }
            float2* ao = aggB + (size_t)(b * NTILE + (NTILE - 1 - tx)) * NP;
            ao[2 * p]     = make_float2(A1a, A2a);
            ao[2 * p + 1] = make_float2(A1b, A2b);
        }
    }

    // ---- stage y to LDS; store (r16-verified mappings) ----
    __syncthreads();
    if (PASS == 0) {
#pragma unroll
        for (int k = 0; k < CM / 2; k++)
            *reinterpret_cast<float2*>(&lds[tid * LDSR + 2 * k]) =
                make_float2(u[2 * k], u[2 * k + 1]);
    } else {
#pragma unroll
        for (int i = 0; i < CM; i++) lds[tid * LDSR + i] = u[i];
    }
    __syncthreads();

    if (PASS == 0) {
        // coalesced REVERSED store of this tile's 2048 samples
        float4* yb4 = reinterpret_cast<float4*>(
            outp + (size_t)b * LPAD + (size_t)(NTILE - 1 - tx) * TILE);
#pragma unroll
        for (int k = 0; k < 8; k++) {
            int o4 = tid + 64 * k;             // 0..511
            int ts = 63 - (o4 >> 3);
            int ih = 31 - 4 * (o4 & 7);
            float2 a  = *reinterpret_cast<const float2*>(&lds[ts * LDSR + ih - 1]);
            float2 b2 = *reinterpret_cast<const float2*>(&lds[ts * LDSR + ih - 3]);
            yb4[o4] = make_float4(a.y, a.x, b2.y, b2.x);
        }
    } else {
        // out[j] = y2[s], j = (LTOT-1-PAD) - s  (un-reverse + trim PAD)
        float* ob = outp + (size_t)b * LX;
        int J0 = (LTOT - 1 - PAD) - tx * TILE;
#pragma unroll
        for (int it = 0; it < CM; it++) {
            int o = it * 64 + tid;
            int j = J0 - o;
            if (j >= 0 && j < LX)
                ob[j] = lds[(o >> 5) * LDSR + (o & 31)];
        }
    }
}

// ---------------------------------------------------------------------------
// Host: scipy butter(8,[500,7000]/8000,'bandpass') -> real 2nd-order sections
// + chunk-transition (A^32) power levels + exact 2048-step const-input pair.
static void compute_coeffs(CoeffsS& C, LvS& L) {
    using cd = std::complex<double>;
    const int N = 8;
    const double sr = 16000.0, lo = 500.0, hi = 7000.0, fs = 2.0;
    double w0 = 2.0 * fs * std::tan(M_PI * (2.0 * lo / sr) / fs);
    double w1 = 2.0 * fs * std::tan(M_PI * (2.0 * hi / sr) / fs);
    double bw = w1 - w0, wo = std::sqrt(w0 * w1);
    cd pbp[16];
    for (int k = 0; k < N; k++) {
        int m = -N + 1 + 2 * k;
        cd pl = -std::exp(cd(0.0, M_PI * m / (2.0 * N)));
        pl *= bw / 2.0;
        cd s = std::sqrt(pl * pl - cd(wo * wo, 0.0));
        pbp[k] = pl + s; pbp[k + N] = pl - s;
    }
    double kbp = std::pow(bw, (double)N);
    const double fs2 = 4.0;
    cd pd[16], denom = 1.0;
    for (int i = 0; i < 16; i++) {
        pd[i] = (cd(fs2, 0.0) + pbp[i]) / (cd(fs2, 0.0) - pbp[i]);
        denom *= (cd(fs2, 0.0) - pbp[i]);
    }
    double kd = kbp * std::real(cd(std::pow(fs2, 8.0), 0.0) / denom);
    cd prodp = 1.0;
    for (int i = 0; i < 16; i++) prodp *= pd[i];
    cd c0 = cd(kd, 0.0) / prodp;
    int n = 0;
    for (int i = 0; i < 16; i++) {
        if (pd[i].imag() <= 0.0) continue;
        cd inv = 1.0 / pd[i];
        cd t1 = cd(1.0, 0.0) - inv, t2 = cd(1.0, 0.0) + inv;
        cd numr = cd(kd, 0.0);
        for (int k = 0; k < 8; k++) numr *= t1;
        for (int k = 0; k < 8; k++) numr *= t2;
        cd den = 1.0;
        for (int j = 0; j < 16; j++)
            if (j != i) den *= (cd(1.0, 0.0) - pd[j] * inv);
        cd r2 = 2.0 * numr / den;             // conjugate pair folded
        if (n < NP) {
            double a1 = 2.0 * pd[i].real();
            double a2 = -std::norm(pd[i]);
            C.a1[n] = (float)a1; C.a2[n] = (float)a2;
            C.b0[n] = (float)r2.real();
            C.b1[n] = (float)(-(r2.real() * pd[i].real() + r2.imag() * pd[i].imag()));
            // exact 2048-step constant-input response pair (prefixB correction)
            double gw1 = 0.0, gw2 = 0.0;
            for (int k = 0; k < 2048; k++) {
                double gt = a1 * gw1 + a2 * gw2 + 1.0; gw2 = gw1; gw1 = gt;
            }
            C.g1a[n] = (float)gw1; C.g1b[n] = (float)gw2;
            double M[4] = { a1, a2, 1.0, 0.0 };       // A = [[a1,a2],[1,0]]
            for (int s = 0; s < 5; s++) {             // M0 = A^32
                double q0 = M[0] * M[0] + M[1] * M[2], q1 = M[0] * M[1] + M[1] * M[3];
                double q2 = M[2] * M[0] + M[3] * M[2], q3 = M[2] * M[1] + M[3] * M[3];
                M[0] = q0; M[1] = q1; M[2] = q2; M[3] = q3;
            }
            for (int k = 0; k < 7; k++) {             // lv[k] = M0^(2^k)
                for (int j = 0; j < 4; j++) L.lv[k][n][j] = (float)M[j];
                double q0 = M[0] * M[0] + M[1] * M[2], q1 = M[0] * M[1] + M[1] * M[3];
                double q2 = M[2] * M[0] + M[3] * M[2], q3 = M[2] * M[1] + M[3] * M[3];
                M[0] = q0; M[1] = q1; M[2] = q2; M[3] = q3;
            }
            n++;
        }
    }
    C.c0 = (float)c0.real();
}

extern "C" void kernel_launch(void* const* d_in, const int* in_sizes, int n_in,
                              void* d_out, int out_size, void* d_ws, size_t ws_size,
                              hipStream_t stream) {
    const float* audio = (const float*)d_in[0];
    float* out = (float*)d_out;

    CoeffsS C; LvS L;
    compute_coeffs(C, L);

    // ws: ybuf 33.8MB + mt 8KB + aggA/aggB/xpreA/xpreB 264KB each
    char* ws = (char*)d_ws;
    size_t o = 0;
    auto alloc = [&](size_t bytes) { size_t r = o; o += (bytes + 255) & ~(size_t)255; return r; };
    float*  ybuf  = (float*)(ws + alloc((size_t)NB * LPAD * sizeof(float)));
    float4* mt    = (float4*)(ws + alloc(512 * sizeof(float4)));
    float2* aggA  = (float2*)(ws + alloc((size_t)NB * NTILE * NP * sizeof(float2)));
    float2* aggB  = (float2*)(ws + alloc((size_t)NB * NTILE * NP * sizeof(float2)));
    float2* xpreA = (float2*)(ws + alloc((size_t)NB * NTILE * NP * sizeof(float2)));
    float2* xpreB = (float2*)(ws + alloc((size_t)NB * NTILE * NP * sizeof(float2)));

    dim3 blkw(64), blk(256), g(NTILE, NB);

    k_init     <<<2,  256, 0, stream>>>(mt, L);
    k_agg      <<<g,  blkw, 0, stream>>>(audio, aggA, mt, C, L);
    k_prefix<0><<<NB, blk,  0, stream>>>(aggA, xpreA, ybuf, C, L);
    k_full<0>  <<<g,  blkw, 0, stream>>>(audio, ybuf, xpreA, aggB, mt, C, L);
    k_prefix<1><<<NB, blk,  0, stream>>>(aggB, xpreB, ybuf, C, L);
    k_full<1>  <<<g,  blkw, 0, stream>>>(ybuf, out, xpreB, nullptr, mt, C, L);
}

// Round 19
// 72.403 us; speedup vs baseline: 1.5551x; 1.4134x over previous
//
#include <hip/hip_runtime.h>
#include <cmath>
#include <complex>

// sr=16000, band 500-7000, order 8 -> 16 poles = 8 real 2nd-order sections.
#define NB    32
#define LX    262144
#define PAD   51                      // padlen = 3*17
#define LTOT  (LX + 2 * PAD)          // 262246
#define CM    32                      // samples per chunk (= per thread)
#define F_PAD 1946                    // zero-input front pad
#define LPAD  (LTOT + F_PAD)          // 264192 = 129 * 2048 (tile-aligned)
#define CPB   64                      // threads per block = ONE WAVE
#define TILE  (CPB * CM)              // 2048 samples per wave-tile
#define NTILE (LPAD / TILE)           // 129 tiles per row
#define NP    8
#define LDSR  34                      // floats per LDS lane-row (proven: 0 conflicts)
#define WIN   16                      // warmup window (chunks); A^512 ~ 2e-8

struct CoeffsS { float a1[NP], a2[NP], b0[NP], b1[NP], c0; };
// lv[k][q] = (A_q^CM)^(2^k) = M0^(2^k), k=0..5 (for k_init binary exp)
struct LvS { float lv[6][NP][4]; };

// ---------------------------------------------------------------------------
// init: build mt[t*8+q] = M0^t (t=0..63) via binary exponentiation.
__global__ void k_init(float4* __restrict__ mt, LvS L) {
    int id = blockIdx.x * 256 + threadIdx.x;
    if (id >= 512) return;
    int t = id >> 3, q = id & 7;
    float m0 = 1.f, m1 = 0.f, m2 = 0.f, m3 = 1.f;
    for (int k = 0; k < 6; k++)
        if ((t >> k) & 1) {
            float a0 = L.lv[k][q][0], a1 = L.lv[k][q][1];
            float a2 = L.lv[k][q][2], a3 = L.lv[k][q][3];
            float n0 = a0 * m0 + a1 * m2, n1 = a0 * m1 + a1 * m3;
            float n2 = a2 * m0 + a3 * m2, n3 = a2 * m1 + a3 * m3;
            m0 = n0; m1 = n1; m2 = n2; m3 = n3;
        }
    mt[id] = make_float4(m0, m1, m2, m3);
}

// ---------------------------------------------------------------------------
// u-loader pass A: chunk c covers t' = c*CM..+CM, real t = t' - F_PAD.
// Safe for negative c (all-pad -> u=0).
__device__ __forceinline__ void load_uA(const float* __restrict__ x,
                                        float base, int c, float (&u)[CM]) {
    int t0 = c * CM - F_PAD;
    if (t0 >= PAD && t0 + CM <= PAD + LX) {
        const float* xs = x + (t0 - PAD);
#pragma unroll
        for (int m = 0; m < CM / 4; m++) {
            float4 v = *reinterpret_cast<const float4*>(xs + 4 * m);
            u[4 * m] = v.x - base; u[4 * m + 1] = v.y - base;
            u[4 * m + 2] = v.z - base; u[4 * m + 3] = v.w - base;
        }
    } else {
#pragma unroll
        for (int i = 0; i < CM; i++) {
            int t = t0 + i;
            float uu;
            if (t < 0) uu = 0.f;                        // front pad
            else {
                float e;
                if (t < PAD)            e = 2.0f * x[0] - x[PAD - t];
                else if (t < PAD + LX)  e = x[t - PAD];
                else                    e = 2.0f * x[LX - 1] - x[2 * LX + PAD - 2 - t];
                uu = e - base;
            }
            u[i] = uu;
        }
    }
}

// u-loader pass B: chunk c from reversed-y buffer minus base; c<0 -> u=0.
__device__ __forceinline__ void load_uB(const float* __restrict__ yb,
                                        float base, int c, float (&u)[CM]) {
    if (c < 0) {
#pragma unroll
        for (int i = 0; i < CM; i++) u[i] = 0.f;
        return;
    }
    const float* ys = yb + (size_t)c * CM;
#pragma unroll
    for (int m = 0; m < CM / 4; m++) {
        float4 v = *reinterpret_cast<const float4*>(ys + 4 * m);
        u[4 * m] = v.x - base; u[4 * m + 1] = v.y - base;
        u[4 * m + 2] = v.z - base; u[4 * m + 3] = v.w - base;
    }
}

// local chunk recurrence from zero state
__device__ __forceinline__ void local_states(const float (&u)[CM], const CoeffsS& C,
                                             float (&w1)[NP], float (&w2)[NP]) {
#pragma unroll
    for (int q = 0; q < NP; q++) { w1[q] = 0.f; w2[q] = 0.f; }
#pragma unroll
    for (int i = 0; i < CM; i++) {
        float uu = u[i];
#pragma unroll
        for (int q = 0; q < NP; q++) {
            float wt = fmaf(C.a1[q], w1[q], fmaf(C.a2[q], w2[q], uu));
            w2[q] = w1[q]; w1[q] = wt;
        }
    }
}

// pack per-lane chunk states: sc4[p*80+j] = (w1[2p],w2[2p],w1[2p+1],w2[2p+1])
__device__ __forceinline__ void pack_states(float4* sc4, int j,
                                            const float (&w1)[NP], const float (&w2)[NP]) {
#pragma unroll
    for (int p = 0; p < 4; p++)
        sc4[p * 80 + j] = make_float4(w1[2 * p], w2[2 * p], w1[2 * p + 1], w2[2 * p + 1]);
}

// ---------------------------------------------------------------------------
// The whole filtfilt direction in ONE kernel type (3 dispatches total):
// warmup chunks give the tile entry state directly (A^512 truncation,
// HW-validated r18: absmax identical to exact scan).
// PASS 0: in=audio -> ybuf reversed.  PASS 1: in=ybuf -> out (rev+trim).
template <int PASS>
__global__ __launch_bounds__(64) void k_full(const float* __restrict__ in,
                                             float* __restrict__ outp,
                                             const float4* __restrict__ mt,
                                             CoeffsS C) {
    __shared__ __align__(16) float lds[CPB * LDSR];   // 8704 B
    float4* sc4 = reinterpret_cast<float4*>(lds);     // 4*80 float4 = 5120 B
    int tid = threadIdx.x, tx = blockIdx.x, b = blockIdx.y;
    int c = tx * CPB + tid;

    const float* x = in + (size_t)b * (PASS == 0 ? LX : LPAD);
    float base = (PASS == 0) ? (2.0f * x[0] - x[PAD]) : x[0];

    // ---- warmup: lanes<WIN compute chunk tx*64-WIN+tid (prev tile tail) ----
    if (tid < WIN) {
        float uw[CM];
        int cw = tx * CPB - WIN + tid;
        if (PASS == 0) load_uA(x, base, cw, uw);
        else           load_uB(x, base, cw, uw);
        float w1[NP], w2[NP];
        local_states(uw, C, w1, w2);
        pack_states(sc4, tid, w1, w2);
    }

    // ---- primary chunk ----
    float u[CM];
    if (PASS == 0) load_uA(x, base, c, u);
    else           load_uB(x, base, c, u);
    float w1[NP], w2[NP];
    local_states(u, C, w1, w2);
    pack_states(sc4, WIN + tid, w1, w2);
    __syncthreads();

    // ---- window combine: entry = sum_{k=1..WIN} M0^(k-1) f[WIN+tid-k] ----
    float e1[NP], e2[NP];
#pragma unroll
    for (int q = 0; q < NP; q++) { e1[q] = 0.f; e2[q] = 0.f; }
#pragma unroll
    for (int k = 1; k <= WIN; k++) {
#pragma unroll
        for (int p = 0; p < 4; p++) {
            float4 f = sc4[p * 80 + WIN + tid - k];
            float4 ma = mt[(k - 1) * NP + 2 * p];
            float4 mb = mt[(k - 1) * NP + 2 * p + 1];
            e1[2 * p]     = fmaf(ma.x, f.x, fmaf(ma.y, f.y, e1[2 * p]));
            e2[2 * p]     = fmaf(ma.z, f.x, fmaf(ma.w, f.y, e2[2 * p]));
            e1[2 * p + 1] = fmaf(mb.x, f.z, fmaf(mb.y, f.w, e1[2 * p + 1]));
            e2[2 * p + 1] = fmaf(mb.z, f.z, fmaf(mb.w, f.w, e2[2 * p + 1]));
        }
    }

    // ---- replay u -> y with entry state (registers) ----
#pragma unroll
    for (int q = 0; q < NP; q++) { w1[q] = e1[q]; w2[q] = e2[q]; }
#pragma unroll
    for (int i = 0; i < CM; i++) {
        float uu = u[i];
        float y = C.c0 * uu;
#pragma unroll
        for (int q = 0; q < NP; q++) {
            float wt = fmaf(C.a1[q], w1[q], fmaf(C.a2[q], w2[q], uu));
            y = fmaf(C.b0[q], wt, fmaf(C.b1[q], w1[q], y));
            w2[q] = w1[q]; w1[q] = wt;
        }
        u[i] = y;                          // u now holds y
    }

    // ---- stage y to LDS; store (r16-verified mappings) ----
    __syncthreads();
    if (PASS == 0) {
#pragma unroll
        for (int k = 0; k < CM / 2; k++)
            *reinterpret_cast<float2*>(&lds[tid * LDSR + 2 * k]) =
                make_float2(u[2 * k], u[2 * k + 1]);
    } else {
#pragma unroll
        for (int i = 0; i < CM; i++) lds[tid * LDSR + i] = u[i];
    }
    __syncthreads();

    if (PASS == 0) {
        // coalesced REVERSED store of this tile's 2048 samples
        float4* yb4 = reinterpret_cast<float4*>(
            outp + (size_t)b * LPAD + (size_t)(NTILE - 1 - tx) * TILE);
#pragma unroll
        for (int k = 0; k < 8; k++) {
            int o4 = tid + 64 * k;             // 0..511
            int ts = 63 - (o4 >> 3);
            int ih = 31 - 4 * (o4 & 7);
            float2 a  = *reinterpret_cast<const float2*>(&lds[ts * LDSR + ih - 1]);
            float2 b2 = *reinterpret_cast<const float2*>(&lds[ts * LDSR + ih - 3]);
            yb4[o4] = make_float4(a.y, a.x, b2.y, b2.x);
        }
    } else {
        // out[j] = y2[s], j = (LTOT-1-PAD) - s  (un-reverse + trim PAD)
        float* ob = outp + (size_t)b * LX;
        int J0 = (LTOT - 1 - PAD) - tx * TILE;
#pragma unroll
        for (int it = 0; it < CM; it++) {
            int o = it * 64 + tid;
            int j = J0 - o;
            if (j >= 0 && j < LX)
                ob[j] = lds[(o >> 5) * LDSR + (o & 31)];
        }
    }
}

// ---------------------------------------------------------------------------
// Host: scipy butter(8,[500,7000]/8000,'bandpass') -> real 2nd-order sections
// + chunk-transition (A^32) power levels (f64, cast to f32).
static void compute_coeffs(CoeffsS& C, LvS& L) {
    using cd = std::complex<double>;
    const int N = 8;
    const double sr = 16000.0, lo = 500.0, hi = 7000.0, fs = 2.0;
    double w0 = 2.0 * fs * std::tan(M_PI * (2.0 * lo / sr) / fs);
    double w1 = 2.0 * fs * std::tan(M_PI * (2.0 * hi / sr) / fs);
    double bw = w1 - w0, wo = std::sqrt(w0 * w1);
    cd pbp[16];
    for (int k = 0; k < N; k++) {
        int m = -N + 1 + 2 * k;
        cd pl = -std::exp(cd(0.0, M_PI * m / (2.0 * N)));
        pl *= bw / 2.0;
        cd s = std::sqrt(pl * pl - cd(wo * wo, 0.0));
        pbp[k] = pl + s; pbp[k + N] = pl - s;
    }
    double kbp = std::pow(bw, (double)N);
    const double fs2 = 4.0;
    cd pd[16], denom = 1.0;
    for (int i = 0; i < 16; i++) {
        pd[i] = (cd(fs2, 0.0) + pbp[i]) / (cd(fs2, 0.0) - pbp[i]);
        denom *= (cd(fs2, 0.0) - pbp[i]);
    }
    double kd = kbp * std::real(cd(std::pow(fs2, 8.0), 0.0) / denom);
    cd prodp = 1.0;
    for (int i = 0; i < 16; i++) prodp *= pd[i];
    cd c0 = cd(kd, 0.0) / prodp;
    int n = 0;
    for (int i = 0; i < 16; i++) {
        if (pd[i].imag() <= 0.0) continue;
        cd inv = 1.0 / pd[i];
        cd t1 = cd(1.0, 0.0) - inv, t2 = cd(1.0, 0.0) + inv;
        cd numr = cd(kd, 0.0);
        for (int k = 0; k < 8; k++) numr *= t1;
        for (int k = 0; k < 8; k++) numr *= t2;
        cd den = 1.0;
        for (int j = 0; j < 16; j++)
            if (j != i) den *= (cd(1.0, 0.0) - pd[j] * inv);
        cd r2 = 2.0 * numr / den;             // conjugate pair folded
        if (n < NP) {
            double a1 = 2.0 * pd[i].real();
            double a2 = -std::norm(pd[i]);
            C.a1[n] = (float)a1; C.a2[n] = (float)a2;
            C.b0[n] = (float)r2.real();
            C.b1[n] = (float)(-(r2.real() * pd[i].real() + r2.imag() * pd[i].imag()));
            double M[4] = { a1, a2, 1.0, 0.0 };       // A = [[a1,a2],[1,0]]
            for (int s = 0; s < 5; s++) {             // M0 = A^32
                double q0 = M[0] * M[0] + M[1] * M[2], q1 = M[0] * M[1] + M[1] * M[3];
                double q2 = M[2] * M[0] + M[3] * M[2], q3 = M[2] * M[1] + M[3] * M[3];
                M[0] = q0; M[1] = q1; M[2] = q2; M[3] = q3;
            }
            for (int k = 0; k < 6; k++) {             // lv[k] = M0^(2^k)
                for (int j = 0; j < 4; j++) L.lv[k][n][j] = (float)M[j];
                double q0 = M[0] * M[0] + M[1] * M[2], q1 = M[0] * M[1] + M[1] * M[3];
                double q2 = M[2] * M[0] + M[3] * M[2], q3 = M[2] * M[1] + M[3] * M[3];
                M[0] = q0; M[1] = q1; M[2] = q2; M[3] = q3;
            }
            n++;
        }
    }
    C.c0 = (float)c0.real();
}

extern "C" void kernel_launch(void* const* d_in, const int* in_sizes, int n_in,
                              void* d_out, int out_size, void* d_ws, size_t ws_size,
                              hipStream_t stream) {
    const float* audio = (const float*)d_in[0];
    float* out = (float*)d_out;

    CoeffsS C; LvS L;
    compute_coeffs(C, L);

    // ws: ybuf 33.8MB + mt 8KB
    char* ws = (char*)d_ws;
    size_t o = 0;
    auto alloc = [&](size_t bytes) { size_t r = o; o += (bytes + 255) & ~(size_t)255; return r; };
    float*  ybuf = (float*)(ws + alloc((size_t)NB * LPAD * sizeof(float)));
    float4* mt   = (float4*)(ws + alloc(512 * sizeof(float4)));

    dim3 blkw(64), g(NTILE, NB);

    k_init   <<<2, 256, 0, stream>>>(mt, L);
    k_full<0><<<g, blkw, 0, stream>>>(audio, ybuf, mt, C);
    k_full<1><<<g, blkw, 0, stream>>>(ybuf, out, mt, C);
}

// Round 20
// 66.708 us; speedup vs baseline: 1.6879x; 1.0854x over previous
//
#include <hip/hip_runtime.h>
#include <cmath>
#include <complex>

// sr=16000, band 500-7000, order 8 -> 16 poles = 8 real 2nd-order sections.
#define NB    32
#define LX    262144
#define PAD   51                      // padlen = 3*17
#define LTOT  (LX + 2 * PAD)          // 262246
#define CM    16                      // samples per chunk (= per lane)
#define F_PAD 1946                    // zero-input front pad
#define LPAD  (LTOT + F_PAD)          // 264192 = 258 * 1024 (tile-aligned)
#define TILE  (64 * CM)               // 1024 samples per wave-tile
#define NTILE (LPAD / TILE)           // 258 wave-tiles per row (even)
#define WPB   2                       // wave-tiles per 128-thread block
#define NP    8
#define LDSR  17                      // floats per LDS lane-row (gcd(17,32)=1)
#define WIN   16                      // warmup window (chunks) = 256 samples
#define WREG  1280                    // floats per wave LDS region (5120 B)

struct CoeffsS { float a1[NP], a2[NP], b0[NP], b1[NP], c0; };
// lv[k][q] = (A_q^CM)^(2^k) = M0^(2^k), k=0..5 (k_init binary exp); M0 = A^16
struct LvS { float lv[6][NP][4]; };

// ---------------------------------------------------------------------------
// init: build mt[t*8+q] = M0^t (t=0..63) via binary exponentiation.
__global__ void k_init(float4* __restrict__ mt, LvS L) {
    int id = blockIdx.x * 256 + threadIdx.x;
    if (id >= 512) return;
    int t = id >> 3, q = id & 7;
    float m0 = 1.f, m1 = 0.f, m2 = 0.f, m3 = 1.f;
    for (int k = 0; k < 6; k++)
        if ((t >> k) & 1) {
            float a0 = L.lv[k][q][0], a1 = L.lv[k][q][1];
            float a2 = L.lv[k][q][2], a3 = L.lv[k][q][3];
            float n0 = a0 * m0 + a1 * m2, n1 = a0 * m1 + a1 * m3;
            float n2 = a2 * m0 + a3 * m2, n3 = a2 * m1 + a3 * m3;
            m0 = n0; m1 = n1; m2 = n2; m3 = n3;
        }
    mt[id] = make_float4(m0, m1, m2, m3);
}

// ---------------------------------------------------------------------------
// u-loader pass A: chunk c covers t' = c*CM..+CM, real t = t' - F_PAD.
// Safe for negative c (all-pad -> u=0).
__device__ __forceinline__ void load_uA(const float* __restrict__ x,
                                        float base, int c, float (&u)[CM]) {
    int t0 = c * CM - F_PAD;
    if (t0 >= PAD && t0 + CM <= PAD + LX) {
        const float* xs = x + (t0 - PAD);
#pragma unroll
        for (int m = 0; m < CM / 4; m++) {
            float4 v = *reinterpret_cast<const float4*>(xs + 4 * m);
            u[4 * m] = v.x - base; u[4 * m + 1] = v.y - base;
            u[4 * m + 2] = v.z - base; u[4 * m + 3] = v.w - base;
        }
    } else {
#pragma unroll
        for (int i = 0; i < CM; i++) {
            int t = t0 + i;
            float uu;
            if (t < 0) uu = 0.f;                        // front pad
            else {
                float e;
                if (t < PAD)            e = 2.0f * x[0] - x[PAD - t];
                else if (t < PAD + LX)  e = x[t - PAD];
                else                    e = 2.0f * x[LX - 1] - x[2 * LX + PAD - 2 - t];
                uu = e - base;
            }
            u[i] = uu;
        }
    }
}

// u-loader pass B: chunk c from reversed-y buffer minus base; c<0 -> u=0.
__device__ __forceinline__ void load_uB(const float* __restrict__ yb,
                                        float base, int c, float (&u)[CM]) {
    if (c < 0) {
#pragma unroll
        for (int i = 0; i < CM; i++) u[i] = 0.f;
        return;
    }
    const float* ys = yb + (size_t)c * CM;
#pragma unroll
    for (int m = 0; m < CM / 4; m++) {
        float4 v = *reinterpret_cast<const float4*>(ys + 4 * m);
        u[4 * m] = v.x - base; u[4 * m + 1] = v.y - base;
        u[4 * m + 2] = v.z - base; u[4 * m + 3] = v.w - base;
    }
}

// local chunk recurrence from zero state
__device__ __forceinline__ void local_states(const float (&u)[CM], const CoeffsS& C,
                                             float (&w1)[NP], float (&w2)[NP]) {
#pragma unroll
    for (int q = 0; q < NP; q++) { w1[q] = 0.f; w2[q] = 0.f; }
#pragma unroll
    for (int i = 0; i < CM; i++) {
        float uu = u[i];
#pragma unroll
        for (int q = 0; q < NP; q++) {
            float wt = fmaf(C.a1[q], w1[q], fmaf(C.a2[q], w2[q], uu));
            w2[q] = w1[q]; w1[q] = wt;
        }
    }
}

// pack per-lane chunk states: sc4[p*80+j] = (w1[2p],w2[2p],w1[2p+1],w2[2p+1])
__device__ __forceinline__ void pack_states(float4* sc4, int j,
                                            const float (&w1)[NP], const float (&w2)[NP]) {
#pragma unroll
    for (int p = 0; p < 4; p++)
        sc4[p * 80 + j] = make_float4(w1[2 * p], w2[2 * p], w1[2 * p + 1], w2[2 * p + 1]);
}

// ---------------------------------------------------------------------------
// One filtfilt direction; 2 independent wave-tiles per 128-thread block.
// Entry state from warmup chunks (A^256 window truncation, decay-validated).
// PASS 0: in=audio -> ybuf reversed.  PASS 1: in=ybuf -> out (rev+trim).
template <int PASS>
__global__ __launch_bounds__(128) void k_full(const float* __restrict__ in,
                                              float* __restrict__ outp,
                                              const float4* __restrict__ mt,
                                              CoeffsS C) {
    __shared__ __align__(16) float lds[WPB * WREG];   // 10240 B
    int tid = threadIdx.x, wv = tid >> 6, l = tid & 63;
    int ttx = blockIdx.x * WPB + wv, b = blockIdx.y;
    int c = ttx * 64 + l;
    float* wlds = lds + wv * WREG;
    float4* sc4 = reinterpret_cast<float4*>(wlds);    // 320 float4 = 5120 B

    const float* x = in + (size_t)b * (PASS == 0 ? LX : LPAD);
    float base = (PASS == 0) ? (2.0f * x[0] - x[PAD]) : x[0];

    // ---- warmup: lanes<WIN compute chunk ttx*64-WIN+l (prev tile tail) ----
    if (l < WIN) {
        float uw[CM];
        int cw = ttx * 64 - WIN + l;
        if (PASS == 0) load_uA(x, base, cw, uw);
        else           load_uB(x, base, cw, uw);
        float w1[NP], w2[NP];
        local_states(uw, C, w1, w2);
        pack_states(sc4, l, w1, w2);
    }

    // ---- primary chunk ----
    float u[CM];
    if (PASS == 0) load_uA(x, base, c, u);
    else           load_uB(x, base, c, u);
    float w1[NP], w2[NP];
    local_states(u, C, w1, w2);
    pack_states(sc4, WIN + l, w1, w2);
    __syncthreads();

    // ---- window combine: entry = sum_{k=1..WIN} M0^(k-1) f[WIN+l-k] ----
    float e1[NP], e2[NP];
#pragma unroll
    for (int q = 0; q < NP; q++) { e1[q] = 0.f; e2[q] = 0.f; }
#pragma unroll
    for (int k = 1; k <= WIN; k++) {
#pragma unroll
        for (int p = 0; p < 4; p++) {
            float4 f = sc4[p * 80 + WIN + l - k];
            float4 ma = mt[(k - 1) * NP + 2 * p];
            float4 mb = mt[(k - 1) * NP + 2 * p + 1];
            e1[2 * p]     = fmaf(ma.x, f.x, fmaf(ma.y, f.y, e1[2 * p]));
            e2[2 * p]     = fmaf(ma.z, f.x, fmaf(ma.w, f.y, e2[2 * p]));
            e1[2 * p + 1] = fmaf(mb.x, f.z, fmaf(mb.y, f.w, e1[2 * p + 1]));
            e2[2 * p + 1] = fmaf(mb.z, f.z, fmaf(mb.w, f.w, e2[2 * p + 1]));
        }
    }

    // ---- replay u -> y with entry state (registers) ----
#pragma unroll
    for (int q = 0; q < NP; q++) { w1[q] = e1[q]; w2[q] = e2[q]; }
#pragma unroll
    for (int i = 0; i < CM; i++) {
        float uu = u[i];
        float y = C.c0 * uu;
#pragma unroll
        for (int q = 0; q < NP; q++) {
            float wt = fmaf(C.a1[q], w1[q], fmaf(C.a2[q], w2[q], uu));
            y = fmaf(C.b0[q], wt, fmaf(C.b1[q], w1[q], y));
            w2[q] = w1[q]; w1[q] = wt;
        }
        u[i] = y;                          // u now holds y
    }

    // ---- stage y to LDS (stride-17, r17-verified); store ----
    __syncthreads();
#pragma unroll
    for (int i = 0; i < CM; i++) wlds[l * LDSR + i] = u[i];
    __syncthreads();

    if (PASS == 0) {
        // coalesced REVERSED store of this tile's 1024 samples (r17-verified)
        float4* yb4 = reinterpret_cast<float4*>(
            outp + (size_t)b * LPAD + (size_t)(NTILE - 1 - ttx) * TILE);
#pragma unroll
        for (int k = 0; k < 4; k++) {
            int o4 = l + 64 * k;               // 0..255
            int ts = 63 - (o4 >> 2);
            int ih = 15 - 4 * (o4 & 3);
            const float* r = &wlds[ts * LDSR];
            yb4[o4] = make_float4(r[ih], r[ih - 1], r[ih - 2], r[ih - 3]);
        }
    } else {
        // out[j] = y2[s], j = (LTOT-1-PAD) - s  (un-reverse + trim, r17-verified)
        float* ob = outp + (size_t)b * LX;
        int J0 = (LTOT - 1 - PAD) - ttx * TILE;
#pragma unroll
        for (int it = 0; it < CM; it++) {
            int o = it * 64 + l;
            int j = J0 - o;
            if (j >= 0 && j < LX)
                ob[j] = wlds[(o >> 4) * LDSR + (o & 15)];
        }
    }
}

// ---------------------------------------------------------------------------
// Host: scipy butter(8,[500,7000]/8000,'bandpass') -> real 2nd-order sections
// + chunk-transition (A^16) power levels (f64, cast to f32).
static void compute_coeffs(CoeffsS& C, LvS& L) {
    using cd = std::complex<double>;
    const int N = 8;
    const double sr = 16000.0, lo = 500.0, hi = 7000.0, fs = 2.0;
    double w0 = 2.0 * fs * std::tan(M_PI * (2.0 * lo / sr) / fs);
    double w1 = 2.0 * fs * std::tan(M_PI * (2.0 * hi / sr) / fs);
    double bw = w1 - w0, wo = std::sqrt(w0 * w1);
    cd pbp[16];
    for (int k = 0; k < N; k++) {
        int m = -N + 1 + 2 * k;
        cd pl = -std::exp(cd(0.0, M_PI * m / (2.0 * N)));
        pl *= bw / 2.0;
        cd s = std::sqrt(pl * pl - cd(wo * wo, 0.0));
        pbp[k] = pl + s; pbp[k + N] = pl - s;
    }
    double kbp = std::pow(bw, (double)N);
    const double fs2 = 4.0;
    cd pd[16], denom = 1.0;
    for (int i = 0; i < 16; i++) {
        pd[i] = (cd(fs2, 0.0) + pbp[i]) / (cd(fs2, 0.0) - pbp[i]);
        denom *= (cd(fs2, 0.0) - pbp[i]);
    }
    double kd = kbp * std::real(cd(std::pow(fs2, 8.0), 0.0) / denom);
    cd prodp = 1.0;
    for (int i = 0; i < 16; i++) prodp *= pd[i];
    cd c0 = cd(kd, 0.0) / prodp;
    int n = 0;
    for (int i = 0; i < 16; i++) {
        if (pd[i].imag() <= 0.0) continue;
        cd inv = 1.0 / pd[i];
        cd t1 = cd(1.0, 0.0) - inv, t2 = cd(1.0, 0.0) + inv;
        cd numr = cd(kd, 0.0);
        for (int k = 0; k < 8; k++) numr *= t1;
        for (int k = 0; k < 8; k++) numr *= t2;
        cd den = 1.0;
        for (int j = 0; j < 16; j++)
            if (j != i) den *= (cd(1.0, 0.0) - pd[j] * inv);
        cd r2 = 2.0 * numr / den;             // conjugate pair folded
        if (n < NP) {
            double a1 = 2.0 * pd[i].real();
            double a2 = -std::norm(pd[i]);
            C.a1[n] = (float)a1; C.a2[n] = (float)a2;
            C.b0[n] = (float)r2.real();
            C.b1[n] = (float)(-(r2.real() * pd[i].real() + r2.imag() * pd[i].imag()));
            double M[4] = { a1, a2, 1.0, 0.0 };       // A = [[a1,a2],[1,0]]
            for (int s = 0; s < 4; s++) {             // M0 = A^16
                double q0 = M[0] * M[0] + M[1] * M[2], q1 = M[0] * M[1] + M[1] * M[3];
                double q2 = M[2] * M[0] + M[3] * M[2], q3 = M[2] * M[1] + M[3] * M[3];
                M[0] = q0; M[1] = q1; M[2] = q2; M[3] = q3;
            }
            for (int k = 0; k < 6; k++) {             // lv[k] = M0^(2^k)
                for (int j = 0; j < 4; j++) L.lv[k][n][j] = (float)M[j];
                double q0 = M[0] * M[0] + M[1] * M[2], q1 = M[0] * M[1] + M[1] * M[3];
                double q2 = M[2] * M[0] + M[3] * M[2], q3 = M[2] * M[1] + M[3] * M[3];
                M[0] = q0; M[1] = q1; M[2] = q2; M[3] = q3;
            }
            n++;
        }
    }
    C.c0 = (float)c0.real();
}

extern "C" void kernel_launch(void* const* d_in, const int* in_sizes, int n_in,
                              void* d_out, int out_size, void* d_ws, size_t ws_size,
                              hipStream_t stream) {
    const float* audio = (const float*)d_in[0];
    float* out = (float*)d_out;

    CoeffsS C; LvS L;
    compute_coeffs(C, L);

    // ws: ybuf 33.8MB + mt 8KB
    char* ws = (char*)d_ws;
    size_t o = 0;
    auto alloc = [&](size_t bytes) { size_t r = o; o += (bytes + 255) & ~(size_t)255; return r; };
    float*  ybuf = (float*)(ws + alloc((size_t)NB * LPAD * sizeof(float)));
    float4* mt   = (float4*)(ws + alloc(512 * sizeof(float4)));

    dim3 blk(128), g(NTILE / WPB, NB);

    k_init   <<<2, 256, 0, stream>>>(mt, L);
    k_full<0><<<g, blk, 0, stream>>>(audio, ybuf, mt, C);
    k_full<1><<<g, blk, 0, stream>>>(ybuf, out, mt, C);
}